// Round 1
// baseline (107.702 us; speedup 1.0000x reference)
//
#include <hip/hip_runtime.h>
#include <hip/hip_bf16.h>

// Problem constants
#define BB 2
#define NN 512
#define P0 16
#define P1 32
#define P2 32
#define HH 128

typedef __attribute__((ext_vector_type(8))) short bf16x8;
typedef __attribute__((ext_vector_type(4))) float f32x4;

__device__ __forceinline__ short f2b(float f) {
  // f32 -> bf16 round-to-nearest-even
  unsigned u = __builtin_bit_cast(unsigned, f);
  u = (u + 0x7FFFu + ((u >> 16) & 1u)) >> 16;
  return (short)u;
}

__device__ __forceinline__ float sigm(float x) {
  return __builtin_amdgcn_rcpf(1.0f + __expf(-x));
}

__device__ __forceinline__ bf16x8 pack2(f32x4 a, f32x4 b) {
  bf16x8 r;
  r[0] = f2b(a[0]); r[1] = f2b(a[1]); r[2] = f2b(a[2]); r[3] = f2b(a[3]);
  r[4] = f2b(b[0]); r[5] = f2b(b[1]); r[6] = f2b(b[2]); r[7] = f2b(b[3]);
  return r;
}

// ---------------------------------------------------------------------------
// Arity-2: out2[b,i,j,:] = mlp(concat[x2[b,i,j,:], x1[b,i,:], x2[b,j,i,:], x1[b,j,:]])
// MLP: 128 -> 128 (sigmoid) -> 32 (sigmoid), via bf16 MFMA 16x16x32.
// Computed transposed (D1^T = W1^T @ IN^T) so GEMM1's output fragment layout
// feeds GEMM2's B operand in-register.
// k-map used consistently for BOTH operands of each GEMM:
//   g(b,e) = 4b + (e&3) + 16*(e>>2)   (any consistent bijection is correct)
// ---------------------------------------------------------------------------
__global__ __launch_bounds__(256) void k_arity2(
    const float* __restrict__ x1, const float* __restrict__ x2,
    const float* __restrict__ W1, const float* __restrict__ b1,
    const float* __restrict__ W2, const float* __restrict__ b2,
    float* __restrict__ out2) {
  __shared__ __align__(16) short lw[32 * 64 * 8];  // W1 frags: 32 KiB

  const int tid = threadIdx.x;
  const int bid = blockIdx.x;       // 0..2047
  const int b  = bid >> 10;         // 0..1
  const int i  = (bid >> 1) & 511;  // 0..511
  const int jh = bid & 1;           // half of j range

  // Stage W1 fragments to LDS (pre-swizzled to MFMA fragment order).
  for (int c = tid; c < 2048; c += 256) {
    const int l = c & 63, th = (c >> 6) & 7, s = c >> 9;
    const int fm = l & 15, fb = l >> 4;
    const int h = 16 * th + fm;
    short* dst = &lw[c * 8];
#pragma unroll
    for (int e = 0; e < 8; ++e) {
      const int k = 32 * s + 4 * fb + (e & 3) + 16 * (e >> 2);
      dst[e] = f2b(W1[k * HH + h]);
    }
  }

  const int lane = tid & 63;
  const int wv = tid >> 6;
  const int m = lane & 15, bq = lane >> 4;

  // W2^T fragments in registers: A2[p][h], p = 16*pt + m, h = 32*s + g(bq,e)
  bf16x8 w2f[2][4];
#pragma unroll
  for (int pt = 0; pt < 2; ++pt) {
#pragma unroll
    for (int s = 0; s < 4; ++s) {
      const int p = 16 * pt + m;
#pragma unroll
      for (int e = 0; e < 8; ++e) {
        const int h = 32 * s + 4 * bq + (e & 3) + 16 * (e >> 2);
        w2f[pt][s][e] = f2b(W2[h * P2 + p]);
      }
    }
  }

  // Bias fragments (match D layout: row = 16*t + 4*bq + r)
  f32x4 bias1[8];
#pragma unroll
  for (int th = 0; th < 8; ++th)
#pragma unroll
    for (int r = 0; r < 4; ++r) bias1[th][r] = b1[16 * th + 4 * bq + r];
  f32x4 bias2[2];
#pragma unroll
  for (int pt = 0; pt < 2; ++pt)
#pragma unroll
    for (int r = 0; r < 4; ++r) bias2[pt][r] = b2[16 * pt + 4 * bq + r];

  // x1[b,i,:] fragment (k-step s=1), constant over j
  const float* x1bi = x1 + ((size_t)b * NN + i) * P1;
  const bf16x8 f1 = pack2(*(const f32x4*)(x1bi + 4 * bq),
                          *(const f32x4*)(x1bi + 16 + 4 * bq));

  __syncthreads();

  const bf16x8* wl = (const bf16x8*)lw;

  for (int it = 0; it < 4; ++it) {
    const int j = jh * 256 + it * 64 + wv * 16 + m;  // this lane's row
    const float* p0 = x2 + (((size_t)b * NN + i) * NN + j) * P2;  // x2[b,i,j,:]
    const float* p2 = x2 + (((size_t)b * NN + j) * NN + i) * P2;  // x2[b,j,i,:]
    const float* p3 = x1 + ((size_t)b * NN + j) * P1;             // x1[b,j,:]
    const bf16x8 f0 = pack2(*(const f32x4*)(p0 + 4 * bq), *(const f32x4*)(p0 + 16 + 4 * bq));
    const bf16x8 f2 = pack2(*(const f32x4*)(p2 + 4 * bq), *(const f32x4*)(p2 + 16 + 4 * bq));
    const bf16x8 f3 = pack2(*(const f32x4*)(p3 + 4 * bq), *(const f32x4*)(p3 + 16 + 4 * bq));

    // GEMM1: D1^T[h][j] ; acc[th] reg r holds h = 16*th + 4*bq + r, col j
    f32x4 acc[8];
#pragma unroll
    for (int th = 0; th < 8; ++th) acc[th] = bias1[th];
#pragma unroll
    for (int s = 0; s < 4; ++s) {
      const bf16x8 bf = (s == 0) ? f0 : (s == 1) ? f1 : (s == 2) ? f2 : f3;
#pragma unroll
      for (int th = 0; th < 8; ++th) {
        const bf16x8 a = wl[(s * 8 + th) * 64 + lane];
        acc[th] = __builtin_amdgcn_mfma_f32_16x16x32_bf16(a, bf, acc[th], 0, 0, 0);
      }
    }

    // GEMM2: out^T[p][j] = W2^T @ sigmoid(D1^T). B2 frag s: elems 0-3 from
    // h-tile 2s, elems 4-7 from h-tile 2s+1 (in-register, same lane).
    f32x4 acc2[2];
#pragma unroll
    for (int pt = 0; pt < 2; ++pt) acc2[pt] = bias2[pt];
#pragma unroll
    for (int s = 0; s < 4; ++s) {
      bf16x8 bf;
#pragma unroll
      for (int e = 0; e < 4; ++e) {
        bf[e]     = f2b(sigm(acc[2 * s][e]));
        bf[4 + e] = f2b(sigm(acc[2 * s + 1][e]));
      }
#pragma unroll
      for (int pt = 0; pt < 2; ++pt)
        acc2[pt] = __builtin_amdgcn_mfma_f32_16x16x32_bf16(w2f[pt][s], bf, acc2[pt], 0, 0, 0);
    }

    // Epilogue: sigmoid + store. acc2[pt] reg r -> p = 16*pt + 4*bq + r, row j.
    float* op = out2 + (((size_t)b * NN + i) * NN + j) * P2;
#pragma unroll
    for (int pt = 0; pt < 2; ++pt) {
      f32x4 o;
#pragma unroll
      for (int r = 0; r < 4; ++r) o[r] = sigm(acc2[pt][r]);
      *(f32x4*)(op + 16 * pt + 4 * bq) = o;
    }
  }
}

// ---------------------------------------------------------------------------
// Arity-1: per (b,i): reduce x2[b,i,:,:] over j (diag masked), then
// out1[b,i,:] = mlp(concat[x1[b,i,:], x0[b,:], rmax2, rmin2])  (112 -> 128 -> 32)
// ---------------------------------------------------------------------------
__global__ __launch_bounds__(256) void k_arity1(
    const float* __restrict__ x0, const float* __restrict__ x1,
    const float* __restrict__ x2, const float* __restrict__ W1,
    const float* __restrict__ b1, const float* __restrict__ W2,
    const float* __restrict__ b2, float* __restrict__ out1) {
  __shared__ float rmx[8][32], rmn[8][32];
  __shared__ float in1[112];
  __shared__ float hid[128];

  const int tid = threadIdx.x;
  const int bid = blockIdx.x;  // 0..1023
  const int b = bid >> 9, i = bid & 511;
  const int p = tid & 31, jg = tid >> 5;

  const float* base = x2 + (((size_t)b * NN + i) * NN) * P2;
  float mx = 0.0f, mn = 1.0f;  // diagonal contributes exactly 0 (max) / 1 (min)
  for (int j = jg; j < NN; j += 8) {
    const float v = base[(size_t)j * P2 + p];
    mx = fmaxf(mx, (j == i) ? 0.0f : v);
    mn = fminf(mn, (j == i) ? 1.0f : v);
  }
  rmx[jg][p] = mx;
  rmn[jg][p] = mn;
  __syncthreads();

  if (tid < 32) {
    float a = rmx[0][tid], c = rmn[0][tid];
#pragma unroll
    for (int g = 1; g < 8; ++g) {
      a = fmaxf(a, rmx[g][tid]);
      c = fminf(c, rmn[g][tid]);
    }
    in1[tid] = x1[((size_t)b * NN + i) * P1 + tid];  // x1 part
    in1[48 + tid] = a;                                // rmax2
    in1[80 + tid] = c;                                // rmin2
  } else if (tid < 48) {
    in1[tid] = x0[b * P0 + (tid - 32)];               // exp0 part
  }
  __syncthreads();

  if (tid < 128) {
    float s = b1[tid];
    for (int k = 0; k < 112; ++k) s += in1[k] * W1[k * HH + tid];
    hid[tid] = sigm(s);
  }
  __syncthreads();

  if (tid < 32) {
    float s = b2[tid];
    for (int k = 0; k < 128; ++k) s += hid[k] * W2[k * P1 + tid];
    out1[((size_t)b * NN + i) * P1 + tid] = sigm(s);
  }
}

// ---------------------------------------------------------------------------
// Arity-0: per b: reduce x1[b,:,:] over n, then
// out0[b,:] = mlp(concat[x0[b,:], rmax1, rmin1])  (80 -> 128 -> 16)
// ---------------------------------------------------------------------------
__global__ __launch_bounds__(256) void k_arity0(
    const float* __restrict__ x0, const float* __restrict__ x1,
    const float* __restrict__ W1, const float* __restrict__ b1,
    const float* __restrict__ W2, const float* __restrict__ b2,
    float* __restrict__ out0) {
  __shared__ float rmx[8][32], rmn[8][32];
  __shared__ float in0[80];
  __shared__ float hid[128];

  const int tid = threadIdx.x;
  const int b = blockIdx.x;  // 0..1
  const int p = tid & 31, jg = tid >> 5;

  float mx = -1e30f, mn = 1e30f;
  for (int j = jg; j < NN; j += 8) {
    const float v = x1[((size_t)b * NN + j) * P1 + p];
    mx = fmaxf(mx, v);
    mn = fminf(mn, v);
  }
  rmx[jg][p] = mx;
  rmn[jg][p] = mn;
  __syncthreads();

  if (tid < 32) {
    float a = rmx[0][tid], c = rmn[0][tid];
#pragma unroll
    for (int g = 1; g < 8; ++g) {
      a = fmaxf(a, rmx[g][tid]);
      c = fminf(c, rmn[g][tid]);
    }
    in0[16 + tid] = a;  // rmax1
    in0[48 + tid] = c;  // rmin1
  } else if (tid < 48) {
    in0[tid - 32] = x0[b * P0 + (tid - 32)];  // x0 part
  }
  __syncthreads();

  if (tid < 128) {
    float s = b1[tid];
    for (int k = 0; k < 80; ++k) s += in0[k] * W1[k * HH + tid];
    hid[tid] = sigm(s);
  }
  __syncthreads();

  if (tid < 16) {
    float s = b2[tid];
    for (int k = 0; k < 128; ++k) s += hid[k] * W2[k * P0 + tid];
    out0[b * P0 + tid] = sigm(s);
  }
}

extern "C" void kernel_launch(void* const* d_in, const int* in_sizes, int n_in,
                              void* d_out, int out_size, void* d_ws, size_t ws_size,
                              hipStream_t stream) {
  const float* x0   = (const float*)d_in[0];
  const float* x1   = (const float*)d_in[1];
  const float* x2   = (const float*)d_in[2];
  const float* W1_0 = (const float*)d_in[3];
  const float* b1_0 = (const float*)d_in[4];
  const float* W2_0 = (const float*)d_in[5];
  const float* b2_0 = (const float*)d_in[6];
  const float* W1_1 = (const float*)d_in[7];
  const float* b1_1 = (const float*)d_in[8];
  const float* W2_1 = (const float*)d_in[9];
  const float* b2_1 = (const float*)d_in[10];
  const float* W1_2 = (const float*)d_in[11];
  const float* b1_2 = (const float*)d_in[12];
  const float* W2_2 = (const float*)d_in[13];
  const float* b2_2 = (const float*)d_in[14];

  float* out0 = (float*)d_out;
  float* out1 = out0 + (size_t)BB * P0;
  float* out2 = out1 + (size_t)BB * NN * P1;

  hipLaunchKernelGGL(k_arity2, dim3(2048), dim3(256), 0, stream,
                     x1, x2, W1_2, b1_2, W2_2, b2_2, out2);
  hipLaunchKernelGGL(k_arity1, dim3(1024), dim3(256), 0, stream,
                     x0, x1, x2, W1_1, b1_1, W2_1, b2_1, out1);
  hipLaunchKernelGGL(k_arity0, dim3(2), dim3(256), 0, stream,
                     x0, x1, W1_0, b1_0, W2_0, b2_0, out0);
}

// Round 3
// 95.475 us; speedup vs baseline: 1.1281x; 1.1281x over previous
//
#include <hip/hip_runtime.h>
#include <hip/hip_bf16.h>

// Problem constants
#define BB 2
#define NN 512
#define P0 16
#define P1 32
#define P2 32
#define HH 128

typedef __attribute__((ext_vector_type(8))) short bf16x8;
typedef __attribute__((ext_vector_type(4))) float f32x4;

__device__ __forceinline__ short f2b(float f) {
  // f32 -> bf16 round-to-nearest-even (verified correct in round 1)
  unsigned u = __builtin_bit_cast(unsigned, f);
  u = (u + 0x7FFFu + ((u >> 16) & 1u)) >> 16;
  return (short)u;
}

__device__ __forceinline__ float sigm(float x) {
  return __builtin_amdgcn_rcpf(1.0f + __expf(-x));
}

__device__ __forceinline__ bf16x8 pack2(f32x4 a, f32x4 b) {
  bf16x8 r;
  r[0] = f2b(a[0]); r[1] = f2b(a[1]); r[2] = f2b(a[2]); r[3] = f2b(a[3]);
  r[4] = f2b(b[0]); r[5] = f2b(b[1]); r[6] = f2b(b[2]); r[7] = f2b(b[3]);
  return r;
}

// ---------------------------------------------------------------------------
// Arity-2: out2[b,i,j,:] = mlp(concat[x2[b,i,j,:], x1[b,i,:], x2[b,j,i,:], x1[b,j,:]])
// 128 -> 128 (sigmoid) -> 32 (sigmoid) via bf16 MFMA 16x16x32, transposed GEMMs.
// Round-1-verified hot path (manual f2b packing, bias1 accumulator-init) +
// next-iteration prefetch + fused per-(b,i,jh) max/min partials -> wsred.
// ---------------------------------------------------------------------------
__global__ __launch_bounds__(256) void k_arity2(
    const float* __restrict__ x1, const float* __restrict__ x2,
    const float* __restrict__ W1, const float* __restrict__ b1,
    const float* __restrict__ W2, const float* __restrict__ b2,
    float* __restrict__ out2, float* __restrict__ wsred) {
  __shared__ __align__(16) short lw[32 * 64 * 8];  // W1 frags: 32 KiB
  __shared__ float pm[4][32], pn[4][32];           // per-wave reduction partials

  const int tid = threadIdx.x;
  const int bid = blockIdx.x;       // 0..2047
  const int b  = bid >> 10;         // 0..1
  const int i  = (bid >> 1) & 511;  // 0..511
  const int jh = bid & 1;           // half of j range

  // Stage W1 fragments to LDS (pre-swizzled to MFMA fragment order).
  for (int c = tid; c < 2048; c += 256) {
    const int l = c & 63, th = (c >> 6) & 7, s = c >> 9;
    const int fm = l & 15, fb = l >> 4;
    const int h = 16 * th + fm;
    short* dst = &lw[c * 8];
#pragma unroll
    for (int e = 0; e < 8; ++e) {
      const int k = 32 * s + 4 * fb + (e & 3) + 16 * (e >> 2);
      dst[e] = f2b(W1[k * HH + h]);
    }
  }

  const int lane = tid & 63;
  const int wv = tid >> 6;
  const int m = lane & 15, bq = lane >> 4;

  // W2^T fragments in registers: A2[p][h], p = 16*pt + m
  bf16x8 w2f[2][4];
#pragma unroll
  for (int pt = 0; pt < 2; ++pt) {
#pragma unroll
    for (int s = 0; s < 4; ++s) {
      const int p = 16 * pt + m;
#pragma unroll
      for (int e = 0; e < 8; ++e) {
        const int h = 32 * s + 4 * bq + (e & 3) + 16 * (e >> 2);
        w2f[pt][s][e] = f2b(W2[h * P2 + p]);
      }
    }
  }

  // Bias fragments (match D layout: row = 16*t + 4*bq + r)
  f32x4 bias1[8];
#pragma unroll
  for (int th = 0; th < 8; ++th)
#pragma unroll
    for (int r = 0; r < 4; ++r) bias1[th][r] = b1[16 * th + 4 * bq + r];
  f32x4 bias2[2];
#pragma unroll
  for (int pt = 0; pt < 2; ++pt)
#pragma unroll
    for (int r = 0; r < 4; ++r) bias2[pt][r] = b2[16 * pt + 4 * bq + r];

  // x1[b,i,:] fragment (k-step s=1), constant over j
  const float* x1bi = x1 + ((size_t)b * NN + i) * P1;
  const bf16x8 f1 = pack2(*(const f32x4*)(x1bi + 4 * bq),
                          *(const f32x4*)(x1bi + 16 + 4 * bq));

  __syncthreads();

  const bf16x8* wl = (const bf16x8*)lw;

  // Fused arity-1 reduction partials over this lane's direct rows.
  // Diagonal contributes exactly 0 (max) / 1 (min), matching the reference mask.
  f32x4 pmx0 = {0.f, 0.f, 0.f, 0.f}, pmx1 = {0.f, 0.f, 0.f, 0.f};
  f32x4 pmn0 = {1.f, 1.f, 1.f, 1.f}, pmn1 = {1.f, 1.f, 1.f, 1.f};

  // Prologue: loads for iteration 0
  const int jb = jh * 256 + wv * 16 + m;
  const float* q0 = x2 + (((size_t)b * NN + i) * NN + jb) * P2;
  const float* q2 = x2 + (((size_t)b * NN + jb) * NN + i) * P2;
  const float* q3 = x1 + ((size_t)b * NN + jb) * P1;
  f32x4 c0a = *(const f32x4*)(q0 + 4 * bq), c0b = *(const f32x4*)(q0 + 16 + 4 * bq);
  f32x4 c2a = *(const f32x4*)(q2 + 4 * bq), c2b = *(const f32x4*)(q2 + 16 + 4 * bq);
  f32x4 c3a = *(const f32x4*)(q3 + 4 * bq), c3b = *(const f32x4*)(q3 + 16 + 4 * bq);

#pragma unroll
  for (int it = 0; it < 4; ++it) {
    const int j = jb + it * 64;

    // Prefetch next iteration's raw data (hides L3 gather latency under compute)
    f32x4 n0a = c0a, n0b = c0b, n2a = c2a, n2b = c2b, n3a = c3a, n3b = c3b;
    if (it < 3) {
      const int jn = j + 64;
      const float* p0 = x2 + (((size_t)b * NN + i) * NN + jn) * P2;
      const float* p2 = x2 + (((size_t)b * NN + jn) * NN + i) * P2;
      const float* p3 = x1 + ((size_t)b * NN + jn) * P1;
      n0a = *(const f32x4*)(p0 + 4 * bq); n0b = *(const f32x4*)(p0 + 16 + 4 * bq);
      n2a = *(const f32x4*)(p2 + 4 * bq); n2b = *(const f32x4*)(p2 + 16 + 4 * bq);
      n3a = *(const f32x4*)(p3 + 4 * bq); n3b = *(const f32x4*)(p3 + 16 + 4 * bq);
    }

    // Reduction accumulate on the direct row (raw f32, before packing)
    {
      const bool dg = (j == i);
#pragma unroll
      for (int r = 0; r < 4; ++r) {
        const float va = dg ? 0.0f : c0a[r], vb = dg ? 0.0f : c0b[r];
        const float wa = dg ? 1.0f : c0a[r], wb = dg ? 1.0f : c0b[r];
        pmx0[r] = fmaxf(pmx0[r], va); pmx1[r] = fmaxf(pmx1[r], vb);
        pmn0[r] = fminf(pmn0[r], wa); pmn1[r] = fminf(pmn1[r], wb);
      }
    }

    const bf16x8 f0 = pack2(c0a, c0b);
    const bf16x8 f2 = pack2(c2a, c2b);
    const bf16x8 f3 = pack2(c3a, c3b);

    // GEMM1: D1^T[h][j] ; acc[th] reg r holds h = 16*th + 4*bq + r, col j
    f32x4 acc[8];
#pragma unroll
    for (int th = 0; th < 8; ++th) acc[th] = bias1[th];
#pragma unroll
    for (int s = 0; s < 4; ++s) {
      const bf16x8 bf = (s == 0) ? f0 : (s == 1) ? f1 : (s == 2) ? f2 : f3;
#pragma unroll
      for (int th = 0; th < 8; ++th) {
        const bf16x8 a = wl[(s * 8 + th) * 64 + lane];
        acc[th] = __builtin_amdgcn_mfma_f32_16x16x32_bf16(a, bf, acc[th], 0, 0, 0);
      }
    }

    // GEMM2: out^T[p][j] = W2^T @ sigmoid(D1^T)
    f32x4 acc2[2];
#pragma unroll
    for (int pt = 0; pt < 2; ++pt) acc2[pt] = bias2[pt];
#pragma unroll
    for (int s = 0; s < 4; ++s) {
      bf16x8 bf;
#pragma unroll
      for (int e = 0; e < 4; ++e) {
        bf[e]     = f2b(sigm(acc[2 * s][e]));
        bf[4 + e] = f2b(sigm(acc[2 * s + 1][e]));
      }
#pragma unroll
      for (int pt = 0; pt < 2; ++pt)
        acc2[pt] = __builtin_amdgcn_mfma_f32_16x16x32_bf16(w2f[pt][s], bf, acc2[pt], 0, 0, 0);
    }

    // Epilogue: sigmoid + store. acc2[pt] reg r -> p = 16*pt + 4*bq + r, row j.
    float* op = out2 + (((size_t)b * NN + i) * NN + j) * P2;
#pragma unroll
    for (int pt = 0; pt < 2; ++pt) {
      f32x4 o;
#pragma unroll
      for (int r = 0; r < 4; ++r) o[r] = sigm(acc2[pt][r]);
      *(f32x4*)(op + 16 * pt + 4 * bq) = o;
    }

    c0a = n0a; c0b = n0b; c2a = n2a; c2b = n2b; c3a = n3a; c3b = n3b;
  }

  // Finish fused reduction: butterfly over the 16 m-lanes, then block combine.
  if (wsred) {
#pragma unroll
    for (int msk = 1; msk < 16; msk <<= 1) {
#pragma unroll
      for (int r = 0; r < 4; ++r) {
        pmx0[r] = fmaxf(pmx0[r], __shfl_xor(pmx0[r], msk));
        pmx1[r] = fmaxf(pmx1[r], __shfl_xor(pmx1[r], msk));
        pmn0[r] = fminf(pmn0[r], __shfl_xor(pmn0[r], msk));
        pmn1[r] = fminf(pmn1[r], __shfl_xor(pmn1[r], msk));
      }
    }
    if (m == 0) {
#pragma unroll
      for (int r = 0; r < 4; ++r) {
        pm[wv][4 * bq + r] = pmx0[r];  pm[wv][16 + 4 * bq + r] = pmx1[r];
        pn[wv][4 * bq + r] = pmn0[r];  pn[wv][16 + 4 * bq + r] = pmn1[r];
      }
    }
    __syncthreads();
    if (tid < 32) {
      float a = pm[0][tid], c = pn[0][tid];
#pragma unroll
      for (int g = 1; g < 4; ++g) {
        a = fmaxf(a, pm[g][tid]);
        c = fminf(c, pn[g][tid]);
      }
      const size_t o = (((size_t)b * NN + i) * 2 + jh) * 64;
      wsred[o + tid] = a;
      wsred[o + 32 + tid] = c;
    }
  }
}

// ---------------------------------------------------------------------------
// Arity-1 (fast): partial reductions come from wsred; just the tiny MLP.
// ---------------------------------------------------------------------------
__global__ __launch_bounds__(128) void k_arity1_fast(
    const float* __restrict__ x0, const float* __restrict__ x1,
    const float* __restrict__ wsred, const float* __restrict__ W1,
    const float* __restrict__ b1, const float* __restrict__ W2,
    const float* __restrict__ b2, float* __restrict__ out1) {
  __shared__ float in1[112];
  __shared__ float hid[HH];

  const int tid = threadIdx.x;
  const int bid = blockIdx.x;  // 0..1023
  const int b = bid >> 9, i = bid & 511;
  const size_t o = ((size_t)b * NN + i) * 128;

  if (tid < 32) {
    const float a = fmaxf(wsred[o + tid], wsred[o + 64 + tid]);
    const float c = fminf(wsred[o + 32 + tid], wsred[o + 96 + tid]);
    in1[tid] = x1[((size_t)b * NN + i) * P1 + tid];
    in1[48 + tid] = a;
    in1[80 + tid] = c;
  } else if (tid < 48) {
    in1[tid] = x0[b * P0 + (tid - 32)];
  }
  __syncthreads();

  {
    float s = b1[tid];
    for (int k = 0; k < 112; ++k) s += in1[k] * W1[k * HH + tid];
    hid[tid] = sigm(s);
  }
  __syncthreads();

  if (tid < 32) {
    float s = b2[tid];
    for (int k = 0; k < 128; ++k) s += hid[k] * W2[k * P1 + tid];
    out1[((size_t)b * NN + i) * P1 + tid] = sigm(s);
  }
}

// ---------------------------------------------------------------------------
// Arity-1 (fallback, full x2 scan) — used only if ws is too small.
// ---------------------------------------------------------------------------
__global__ __launch_bounds__(256) void k_arity1(
    const float* __restrict__ x0, const float* __restrict__ x1,
    const float* __restrict__ x2, const float* __restrict__ W1,
    const float* __restrict__ b1, const float* __restrict__ W2,
    const float* __restrict__ b2, float* __restrict__ out1) {
  __shared__ float rmx[8][32], rmn[8][32];
  __shared__ float in1[112];
  __shared__ float hid[128];

  const int tid = threadIdx.x;
  const int bid = blockIdx.x;  // 0..1023
  const int b = bid >> 9, i = bid & 511;
  const int p = tid & 31, jg = tid >> 5;

  const float* base = x2 + (((size_t)b * NN + i) * NN) * P2;
  float mx = 0.0f, mn = 1.0f;
  for (int j = jg; j < NN; j += 8) {
    const float v = base[(size_t)j * P2 + p];
    mx = fmaxf(mx, (j == i) ? 0.0f : v);
    mn = fminf(mn, (j == i) ? 1.0f : v);
  }
  rmx[jg][p] = mx;
  rmn[jg][p] = mn;
  __syncthreads();

  if (tid < 32) {
    float a = rmx[0][tid], c = rmn[0][tid];
#pragma unroll
    for (int g = 1; g < 8; ++g) {
      a = fmaxf(a, rmx[g][tid]);
      c = fminf(c, rmn[g][tid]);
    }
    in1[tid] = x1[((size_t)b * NN + i) * P1 + tid];
    in1[48 + tid] = a;
    in1[80 + tid] = c;
  } else if (tid < 48) {
    in1[tid] = x0[b * P0 + (tid - 32)];
  }
  __syncthreads();

  if (tid < 128) {
    float s = b1[tid];
    for (int k = 0; k < 112; ++k) s += in1[k] * W1[k * HH + tid];
    hid[tid] = sigm(s);
  }
  __syncthreads();

  if (tid < 32) {
    float s = b2[tid];
    for (int k = 0; k < 128; ++k) s += hid[k] * W2[k * P1 + tid];
    out1[((size_t)b * NN + i) * P1 + tid] = sigm(s);
  }
}

// ---------------------------------------------------------------------------
// Arity-0
// ---------------------------------------------------------------------------
__global__ __launch_bounds__(256) void k_arity0(
    const float* __restrict__ x0, const float* __restrict__ x1,
    const float* __restrict__ W1, const float* __restrict__ b1,
    const float* __restrict__ W2, const float* __restrict__ b2,
    float* __restrict__ out0) {
  __shared__ float rmx[8][32], rmn[8][32];
  __shared__ float in0[80];
  __shared__ float hid[128];

  const int tid = threadIdx.x;
  const int b = blockIdx.x;  // 0..1
  const int p = tid & 31, jg = tid >> 5;

  float mx = -1e30f, mn = 1e30f;
  for (int j = jg; j < NN; j += 8) {
    const float v = x1[((size_t)b * NN + j) * P1 + p];
    mx = fmaxf(mx, v);
    mn = fminf(mn, v);
  }
  rmx[jg][p] = mx;
  rmn[jg][p] = mn;
  __syncthreads();

  if (tid < 32) {
    float a = rmx[0][tid], c = rmn[0][tid];
#pragma unroll
    for (int g = 1; g < 8; ++g) {
      a = fmaxf(a, rmx[g][tid]);
      c = fminf(c, rmn[g][tid]);
    }
    in0[16 + tid] = a;
    in0[48 + tid] = c;
  } else if (tid < 48) {
    in0[tid - 32] = x0[b * P0 + (tid - 32)];
  }
  __syncthreads();

  if (tid < 128) {
    float s = b1[tid];
    for (int k = 0; k < 80; ++k) s += in0[k] * W1[k * HH + tid];
    hid[tid] = sigm(s);
  }
  __syncthreads();

  if (tid < 16) {
    float s = b2[tid];
    for (int k = 0; k < 128; ++k) s += hid[k] * W2[k * P0 + tid];
    out0[b * P0 + tid] = sigm(s);
  }
}

extern "C" void kernel_launch(void* const* d_in, const int* in_sizes, int n_in,
                              void* d_out, int out_size, void* d_ws, size_t ws_size,
                              hipStream_t stream) {
  const float* x0   = (const float*)d_in[0];
  const float* x1   = (const float*)d_in[1];
  const float* x2   = (const float*)d_in[2];
  const float* W1_0 = (const float*)d_in[3];
  const float* b1_0 = (const float*)d_in[4];
  const float* W2_0 = (const float*)d_in[5];
  const float* b2_0 = (const float*)d_in[6];
  const float* W1_1 = (const float*)d_in[7];
  const float* b1_1 = (const float*)d_in[8];
  const float* W2_1 = (const float*)d_in[9];
  const float* b2_1 = (const float*)d_in[10];
  const float* W1_2 = (const float*)d_in[11];
  const float* b1_2 = (const float*)d_in[12];
  const float* W2_2 = (const float*)d_in[13];
  const float* b2_2 = (const float*)d_in[14];

  float* out0 = (float*)d_out;
  float* out1 = out0 + (size_t)BB * P0;
  float* out2 = out1 + (size_t)BB * NN * P1;

  const bool use_ws = ws_size >= (size_t)BB * NN * 2 * 64 * sizeof(float);  // 512 KiB
  float* wsred = use_ws ? (float*)d_ws : nullptr;

  hipLaunchKernelGGL(k_arity2, dim3(2048), dim3(256), 0, stream,
                     x1, x2, W1_2, b1_2, W2_2, b2_2, out2, wsred);
  if (use_ws) {
    hipLaunchKernelGGL(k_arity1_fast, dim3(1024), dim3(128), 0, stream,
                       x0, x1, wsred, W1_1, b1_1, W2_1, b2_1, out1);
  } else {
    hipLaunchKernelGGL(k_arity1, dim3(1024), dim3(256), 0, stream,
                       x0, x1, x2, W1_1, b1_1, W2_1, b2_1, out1);
  }
  hipLaunchKernelGGL(k_arity0, dim3(2), dim3(256), 0, stream,
                     x0, x1, W1_0, b1_0, W2_0, b2_0, out0);
}